// Round 1
// 70.842 us; speedup vs baseline: 1.0319x; 1.0319x over previous
//
#include <hip/hip_runtime.h>

typedef _Float16 half4v __attribute__((ext_vector_type(4)));
typedef __fp16 fp16x2 __attribute__((ext_vector_type(2)));
typedef float float4v __attribute__((ext_vector_type(4)));

#define S_ 1024
#define H_ 8
#define B_ 8
#define BH 64           // B*H
#define NROW 8192       // B*S
#define E_ 64
#define VST 1032        // vT row stride (halves)
#define VHALVES (9 * VST)

// Pack 4 floats -> half4v via v_cvt_pkrtz_f16_f32.
static __device__ inline half4v pack4(float a, float b, float c, float d) {
    union { fp16x2 f2[2]; half4v h4; } u;
    u.f2[0] = __builtin_amdgcn_cvt_pkrtz(a, b);
    u.f2[1] = __builtin_amdgcn_cvt_pkrtz(c, d);
    return u.h4;
}

// ---------------------------------------------------------------------------
// fused proj+attn: 256 blocks (bh*4 + q-quarter) x 1024 threads.
// Phase 0: each thread computes ONE s-row's closed-form quantum-head proj
// (8 cos + 8 mul) and writes the kF / vT LDS images DIRECTLY -- no global
// kG/vG round-trip, no staging copy, no separate proj kernel. The 4 blocks
// per bh redundantly recompute proj (cheap: ~0.4us/CU of cos) in exchange
// for dropping 2.2MB global writes + 35MB L2 staging reads + 1 dispatch.
// Phase 1: K-loop byte-identical to the previous best (R10/R14 structure).
//   kF[64*128]: pre-swizzled K/Q-fragments; lanes 32..63 mirror 0..31
//     (garbage k>=8 nullified by qf=0 quads>=2).
//   vT[9*1032]: transposed V rows 0..7 + ones row 8 (l-trick); V-frag cols
//     9..15 mirror 1..7 (junk O^T rows never read).
// mfma1: A=K-frag, B=Q-frag -> S^T == B-layout of P. P = exp2(S), no shift.
// mfma2: A=V'-frag, B=P -> O^T; ones row gives l at lane 32|q, reg 0.
// Grid 256 blocks = 1 block/CU (LDS 34.96 KB), 16 waves/CU (4/SIMD).
// ---------------------------------------------------------------------------
__global__ __launch_bounds__(1024, 4) void fused_attn_kernel(
        const float* __restrict__ x, const float* __restrict__ theta,
        _Float16* __restrict__ attnH) {
    __shared__ _Float16 kF[64 * 128];       // 16384 B
    __shared__ _Float16 vT[VHALVES];        // 18576 B
    int bh = blockIdx.x >> 2;
    int qc = blockIdx.x & 3;
    int b = bh >> 3, h = bh & 7;
    int tid = threadIdx.x;

    // ---- phase 0: proj for ALL s of this bh, straight into LDS ----
    {
        int s = tid;                        // 1024 threads == 1024 s-rows
        const float4* xp = (const float4*)(x + (((size_t)(b << 10) + s) << 6) + (h << 3));
        float4 x0 = xp[0];
        float4 x1 = xp[1];
        float4 t0 = *(const float4*)theta;
        float4 t1 = *(const float4*)(theta + 4);
        float c0 = __cosf(x0.x + t0.x);
        float c1 = __cosf(x0.y + t0.y);
        float c2 = __cosf(x0.z + t0.z);
        float c3 = __cosf(x0.w + t0.w);
        float c4 = __cosf(x1.x + t1.x);
        float c5 = __cosf(x1.y + t1.y);
        float c6 = __cosf(x1.z + t1.z);
        float c7 = __cosf(x1.w + t1.w);
        float e1 = c0 * c1;
        float e2 = e1 * c2;
        float e3 = e2 * c3;
        float e4 = e3 * c4;
        float e5 = e4 * c5;
        float e6 = e5 * c6;
        float e7 = e6 * c7;
        float e0 = ((c1 * c2) * (c3 * c4)) * ((c5 * c6) * c7);
        half4v lo = pack4(e0, e1, e2, e3);
        half4v hi = pack4(e4, e5, e6, e7);
        int kt = s >> 4, c = s & 15;
        *(half4v*)&kF[kt * 128 + c * 4]      = lo;   // lane (q=0,c): d0..3
        *(half4v*)&kF[kt * 128 + 64 + c * 4] = hi;   // lane (q=1,c): d4..7
        // transposed V rows (consecutive u16 across consecutive s)
        vT[0 * VST + s] = lo[0]; vT[1 * VST + s] = lo[1];
        vT[2 * VST + s] = lo[2]; vT[3 * VST + s] = lo[3];
        vT[4 * VST + s] = hi[0]; vT[5 * VST + s] = hi[1];
        vT[6 * VST + s] = hi[2]; vT[7 * VST + s] = hi[3];
        // ones row (l-trick): tid 0..255 cover halves 0..1023
        if (tid < 256) {
            const half4v one = {(_Float16)1.f, (_Float16)1.f, (_Float16)1.f, (_Float16)1.f};
            *(half4v*)&vT[8 * VST + tid * 4] = one;
        }
    }
    __syncthreads();

    // ---- phase 1: attention K-loop (byte-identical to previous best) ----
    int lane = tid & 63;
    int wv   = tid >> 6;                    // 0..15: q-tile within quarter
    int col  = lane & 15;
    int quad = lane >> 4;
    int q0   = qc * 256 + wv * 16;

    bool lo2 = (quad < 2);

    int kbase = (lane & 31) * 4;
    int vcol = (col < 9) ? col : (col - 8);
    int vbase = vcol * VST + quad * 4;

    half4v qf = {(_Float16)0.f, (_Float16)0.f, (_Float16)0.f, (_Float16)0.f};
    if (lo2) qf = *(const half4v*)&kF[kbase + (q0 >> 4) * 128];
    qf *= (_Float16)0.51012921f;            // log2(e)/sqrt(8)

    const float4v zc = {0.f, 0.f, 0.f, 0.f};
    float4v o0 = zc, o1 = zc, o2 = zc, o3 = zc;

#pragma unroll
    for (int kt = 0; kt < 16; ++kt) {
        half4v k0 = *(const half4v*)&kF[kbase + (kt +  0) * 128];
        half4v k1 = *(const half4v*)&kF[kbase + (kt + 16) * 128];
        half4v k2 = *(const half4v*)&kF[kbase + (kt + 32) * 128];
        half4v k3 = *(const half4v*)&kF[kbase + (kt + 48) * 128];
        half4v v0 = *(const half4v*)&vT[vbase + (kt +  0) * 16];
        half4v v1 = *(const half4v*)&vT[vbase + (kt + 16) * 16];
        half4v v2 = *(const half4v*)&vT[vbase + (kt + 32) * 16];
        half4v v3 = *(const half4v*)&vT[vbase + (kt + 48) * 16];
        float4v s0 = __builtin_amdgcn_mfma_f32_16x16x16f16(k0, qf, zc, 0, 0, 0);
        float4v s1 = __builtin_amdgcn_mfma_f32_16x16x16f16(k1, qf, zc, 0, 0, 0);
        float4v s2 = __builtin_amdgcn_mfma_f32_16x16x16f16(k2, qf, zc, 0, 0, 0);
        float4v s3 = __builtin_amdgcn_mfma_f32_16x16x16f16(k3, qf, zc, 0, 0, 0);
        half4v p0 = pack4(__builtin_amdgcn_exp2f(s0[0]), __builtin_amdgcn_exp2f(s0[1]),
                          __builtin_amdgcn_exp2f(s0[2]), __builtin_amdgcn_exp2f(s0[3]));
        half4v p1 = pack4(__builtin_amdgcn_exp2f(s1[0]), __builtin_amdgcn_exp2f(s1[1]),
                          __builtin_amdgcn_exp2f(s1[2]), __builtin_amdgcn_exp2f(s1[3]));
        half4v p2 = pack4(__builtin_amdgcn_exp2f(s2[0]), __builtin_amdgcn_exp2f(s2[1]),
                          __builtin_amdgcn_exp2f(s2[2]), __builtin_amdgcn_exp2f(s2[3]));
        half4v p3 = pack4(__builtin_amdgcn_exp2f(s3[0]), __builtin_amdgcn_exp2f(s3[1]),
                          __builtin_amdgcn_exp2f(s3[2]), __builtin_amdgcn_exp2f(s3[3]));
        o0 = __builtin_amdgcn_mfma_f32_16x16x16f16(v0, p0, o0, 0, 0, 0);
        o1 = __builtin_amdgcn_mfma_f32_16x16x16f16(v1, p1, o1, 0, 0, 0);
        o2 = __builtin_amdgcn_mfma_f32_16x16x16f16(v2, p2, o2, 0, 0, 0);
        o3 = __builtin_amdgcn_mfma_f32_16x16x16f16(v3, p3, o3, 0, 0, 0);
    }

    float4v oacc;
#pragma unroll
    for (int r = 0; r < 4; ++r) oacc[r] = (o0[r] + o1[r]) + (o2[r] + o3[r]);

    float l = __shfl(oacc[0], 32 | col, 64);
    if (lo2) {
        float inv = __builtin_amdgcn_rcpf(l);
        half4v ov = pack4(oacc[0] * inv, oacc[1] * inv, oacc[2] * inv, oacc[3] * inv);
        *(half4v*)(attnH + (((size_t)(b << 10) + q0 + col) << 6) + (h << 3) + quad * 4) = ov;
    }
}

// ---------------------------------------------------------------------------
// combine (unchanged): zero LDS / zero barriers, direct-from-global fragments.
// out[r,e] = sum_k A[r,k]*W[e,k]; A-frag and W-frag are contiguous in
// exactly the MFMA fragment layout. One wave per 16-row m-tile.
// ---------------------------------------------------------------------------
__global__ __launch_bounds__(64) void combine_kernel(
        const _Float16* __restrict__ AH, const float* __restrict__ W,
        float* __restrict__ out) {
    int r0 = blockIdx.x * 16;
    int lane = threadIdx.x;
    int col = lane & 15;
    int quad = lane >> 4;

    half4v af[4];
#pragma unroll
    for (int t = 0; t < 4; ++t)
        af[t] = *(const half4v*)&AH[(size_t)(r0 + col) * 64 + t * 16 + quad * 4];

    float4v acc[4] = {{0,0,0,0},{0,0,0,0},{0,0,0,0},{0,0,0,0}};
#pragma unroll
    for (int e = 0; e < 4; ++e) {
#pragma unroll
        for (int t = 0; t < 4; ++t) {
            float4 w4 = *(const float4*)&W[(size_t)(e * 16 + col) * 64 + t * 16 + quad * 4];
            half4v wf = {(_Float16)w4.x, (_Float16)w4.y, (_Float16)w4.z, (_Float16)w4.w};
            acc[e] = __builtin_amdgcn_mfma_f32_16x16x16f16(af[t], wf, acc[e], 0, 0, 0);
        }
    }

#pragma unroll
    for (int e = 0; e < 4; ++e)
#pragma unroll
        for (int r = 0; r < 4; ++r)
            out[(size_t)(r0 + quad * 4 + r) * E_ + e * 16 + col] = acc[e][r];
}

// ---------------------------------------------------------------------------
extern "C" void kernel_launch(void* const* d_in, const int* in_sizes, int n_in,
                              void* d_out, int out_size, void* d_ws, size_t ws_size,
                              hipStream_t stream) {
    const float* x     = (const float*)d_in[0];   // [8,1024,64] fp32
    const float* theta = (const float*)d_in[1];   // [8]
    const float* W     = (const float*)d_in[2];   // [64,64]
    float* out = (float*)d_out;                   // [8,1024,64]

    _Float16* attnH = (_Float16*)d_ws;            // 1 MB (only ws use now)

    fused_attn_kernel<<<BH * 4, 1024, 0, stream>>>(x, theta, attnH);
    combine_kernel<<<NROW / 16, 64, 0, stream>>>(attnH, W, out);
}